// Round 7
// baseline (471.741 us; speedup 1.0000x reference)
//
#include <hip/hip_runtime.h>
#include <hip/hip_bf16.h>

// N=50000 nodes, IN=256, H=8 heads, D=32, HD=256, E=800000 edges (from in_sizes).

typedef __attribute__((ext_vector_type(8))) short short8;
typedef __attribute__((ext_vector_type(8))) unsigned short ushortx8;
typedef __attribute__((ext_vector_type(4))) unsigned short ushortx4;
typedef __attribute__((ext_vector_type(4))) float floatx4;
typedef __attribute__((ext_vector_type(4))) int intx4;

__device__ __forceinline__ void g2l16(const void* g, void* l) {
    __builtin_amdgcn_global_load_lds(
        (const __attribute__((address_space(1))) unsigned int*)g,
        (__attribute__((address_space(3))) unsigned int*)l, 16, 0, 0);
}

__device__ __forceinline__ float bf2f(unsigned short u) {
    union { unsigned int i; float f; } c; c.i = ((unsigned int)u) << 16; return c.f;
}
__device__ __forceinline__ unsigned short f2bf(float f) {
    __hip_bfloat16 b = __float2bfloat16(f);
    return *reinterpret_cast<unsigned short*>(&b);
}

// ---- fp32 -> bf16 conversions ----
__global__ __launch_bounds__(256) void cvt_bf16(const float* __restrict__ src,
                                                unsigned short* __restrict__ dst, int n4) {
    int i = blockIdx.x * 256 + threadIdx.x;
    if (i >= n4) return;
    floatx4 f = __builtin_nontemporal_load((const floatx4*)src + i);
    ushortx4 u;
    u.x = f2bf(f.x); u.y = f2bf(f.y); u.z = f2bf(f.z); u.w = f2bf(f.w);
    ((ushortx4*)dst)[i] = u;
}

__global__ __launch_bounds__(256) void cvt_w3(const float* __restrict__ Wq,
                                              const float* __restrict__ Wk,
                                              const float* __restrict__ Wv,
                                              unsigned short* __restrict__ Wb, int n4) {
    int mat = blockIdx.y;
    const float* src = (mat == 0) ? Wq : (mat == 1) ? Wk : Wv;
    int i = blockIdx.x * 256 + threadIdx.x;
    if (i >= n4) return;
    floatx4 f = __builtin_nontemporal_load((const floatx4*)src + i);
    ushortx4 u;
    u.x = f2bf(f.x); u.y = f2bf(f.y); u.z = f2bf(f.z); u.w = f2bf(f.w);
    ((ushortx4*)(Wb + (size_t)mat * 65536))[i] = u;
}

// ---- bf16 MFMA QKV projection, BK=64 (two 32-k sub-tiles per barrier) ----
// grid: (ceil(N/128), 6). Block 256 = 4 waves; each wave 64x64 (4x4 MFMA 16x16x32).
// 32 MFMA per barrier pair (vs 16 at BK=32) -> half the barrier drains.
// Q written bf16 NT; K,V bf16 interleaved KV[N][512] ushorts (K at +0, V at +256).
__global__ __launch_bounds__(256) void qkv_gemm_mfma(
    const unsigned short* __restrict__ hb, const unsigned short* __restrict__ Wb,
    const float* __restrict__ bq, const float* __restrict__ bk, const float* __restrict__ bv,
    unsigned short* __restrict__ Qb, unsigned short* __restrict__ KV, int N)
{
    __shared__ unsigned short Ast[2][128 * 32];
    __shared__ unsigned short Bst[2][128 * 32];

    const int tid = threadIdx.x;
    const int wave = tid >> 6;
    const int lane = tid & 63;
    const int m = lane & 15;
    const int q = lane >> 4;
    const int wr = wave >> 1, wc = wave & 1;

    const int mbase = blockIdx.x * 128;
    const int mat = blockIdx.y >> 1;                 // 0:Q 1:K 2:V
    const int colbase = (blockIdx.y & 1) * 128;
    const int wrow0 = blockIdx.y * 128;

    const float* bias = (mat == 0) ? bq : (mat == 1) ? bk : bv;

    floatx4 acc[4][4] = {};

    for (int kk = 0; kk < 256; kk += 64) {
#pragma unroll
        for (int c = 0; c < 2; c++) {
#pragma unroll
            for (int t = 0; t < 2; t++) {
                int f = t * 256 + tid;
                int row = f >> 2, kc = f & 3;
                int grow = mbase + row; if (grow > N - 1) grow = N - 1;
                g2l16(hb + (size_t)grow * 256 + kk + c * 32 + kc * 8,
                      Ast[c] + (size_t)(t * 256 + wave * 64) * 8);
            }
#pragma unroll
            for (int t = 0; t < 2; t++) {
                int f = t * 256 + tid;
                int row = f >> 2, kc = f & 3;
                g2l16(Wb + (size_t)(wrow0 + row) * 256 + kk + c * 32 + kc * 8,
                      Bst[c] + (size_t)(t * 256 + wave * 64) * 8);
            }
        }
        __syncthreads();

#pragma unroll
        for (int c = 0; c < 2; c++) {
            short8 a[4], b[4];
#pragma unroll
            for (int i = 0; i < 4; i++) {
                int r = wr * 64 + i * 16 + m;
                a[i] = *(const short8*)&Ast[c][r * 32 + q * 8];
            }
#pragma unroll
            for (int j = 0; j < 4; j++) {
                int cc = wc * 64 + j * 16 + m;
                b[j] = *(const short8*)&Bst[c][cc * 32 + q * 8];
            }
#pragma unroll
            for (int i = 0; i < 4; i++)
#pragma unroll
                for (int j = 0; j < 4; j++)
                    acc[i][j] = __builtin_amdgcn_mfma_f32_16x16x32_bf16(a[i], b[j], acc[i][j], 0, 0, 0);
        }
        __syncthreads();
    }

    float bvj[4];
#pragma unroll
    for (int j = 0; j < 4; j++) bvj[j] = bias[colbase + wc * 64 + j * 16 + m];

    const int col0 = colbase + wc * 64 + m;
    // C/D layout: col = lane&15, row = (lane>>4)*4 + reg
#pragma unroll
    for (int i = 0; i < 4; i++) {
#pragma unroll
        for (int r = 0; r < 4; r++) {
            int grow = mbase + wr * 64 + i * 16 + q * 4 + r;
            if (grow < N) {
                if (mat == 0) {
                    unsigned short* op = Qb + (size_t)grow * 256 + col0;
#pragma unroll
                    for (int j = 0; j < 4; j++)
                        __builtin_nontemporal_store(f2bf(acc[i][j][r] + bvj[j]), op + j * 16);
                } else {
                    unsigned short* op = KV + (size_t)grow * 512 + ((mat == 2) ? 256 : 0) + col0;
#pragma unroll
                    for (int j = 0; j < 4; j++)
                        op[j * 16] = f2bf(acc[i][j][r] + bvj[j]);
                }
            }
        }
    }
}

// ---- CSR build ----
__global__ void count_deg(const int* __restrict__ dst, int* __restrict__ deg, int E) {
    int e4 = (blockIdx.x * 256 + threadIdx.x) * 4;
    if (e4 + 3 < E) {
        intx4 d = __builtin_nontemporal_load((const intx4*)(dst + e4));
        atomicAdd(&deg[d.x], 1); atomicAdd(&deg[d.y], 1);
        atomicAdd(&deg[d.z], 1); atomicAdd(&deg[d.w], 1);
    } else {
        for (int e = e4; e < E; e++) atomicAdd(&deg[dst[e]], 1);
    }
}

// single-block fused exclusive scan: deg -> offsets, cursor
__global__ __launch_bounds__(1024) void scan_fused(const int* __restrict__ deg,
                                                   int* __restrict__ offsets,
                                                   int* __restrict__ cursor, int N, int E) {
    __shared__ int sums[1024];
    const int per = (N + 1023) / 1024;
    const int base = threadIdx.x * per;
    int sum = 0;
    for (int i = 0; i < per; i++) {
        int idx = base + i;
        if (idx < N) sum += deg[idx];
    }
    sums[threadIdx.x] = sum;
    __syncthreads();
    for (int s = 1; s < 1024; s <<= 1) {
        int v = sums[threadIdx.x];
        int add = (threadIdx.x >= (unsigned)s) ? sums[threadIdx.x - s] : 0;
        __syncthreads();
        sums[threadIdx.x] = v + add;
        __syncthreads();
    }
    int run = (threadIdx.x == 0) ? 0 : sums[threadIdx.x - 1];
    for (int i = 0; i < per; i++) {
        int idx = base + i;
        if (idx < N) {
            offsets[idx] = run; cursor[idx] = run;
            run += deg[idx];
        }
    }
    if (threadIdx.x == 0) offsets[N] = E;
}

// src node ids fit in uint16 (N < 65536): halves scatter/store + index-stream bytes
__global__ void scatter_edges(const int* __restrict__ dst, const int* __restrict__ src,
                              int* __restrict__ cursor, unsigned short* __restrict__ ssorted,
                              int E) {
    int e4 = (blockIdx.x * 256 + threadIdx.x) * 4;
    if (e4 + 3 < E) {
        intx4 d = __builtin_nontemporal_load((const intx4*)(dst + e4));
        intx4 s = __builtin_nontemporal_load((const intx4*)(src + e4));
        ssorted[atomicAdd(&cursor[d.x], 1)] = (unsigned short)s.x;
        ssorted[atomicAdd(&cursor[d.y], 1)] = (unsigned short)s.y;
        ssorted[atomicAdd(&cursor[d.z], 1)] = (unsigned short)s.z;
        ssorted[atomicAdd(&cursor[d.w], 1)] = (unsigned short)s.w;
    } else {
        for (int e = e4; e < E; e++)
            ssorted[atomicAdd(&cursor[dst[e]], 1)] = (unsigned short)src[e];
    }
}

// ---- fused score + segment-softmax + aggregation (r6-proven structure) ----
__global__ __launch_bounds__(256) void edge_agg(
    const unsigned short* __restrict__ Qb, const unsigned short* __restrict__ KV,
    const int* __restrict__ offsets, const unsigned short* __restrict__ ssorted,
    float* __restrict__ out, int N)
{
    const int wave = threadIdx.x >> 6;
    const int lane = threadIdx.x & 63;
    const int half = lane >> 5;
    const int hl = lane & 31;
    const int n = blockIdx.x * 4 + wave;
    if (n >= N) return;

    float q[8];
    {
        ushortx8 qu = __builtin_nontemporal_load((const ushortx8*)(Qb + (size_t)n * 256 + hl * 8));
#pragma unroll
        for (int j = 0; j < 8; j++) q[j] = bf2f(qu[j]);
    }

    float acc[8] = {};
    float z = 0.f;
    const int beg = offsets[n], end = offsets[n + 1];
    const int len = end - beg;
    const int mid = beg + ((len + 1) >> 1);
    const float scale = 0.17677669529663687f;  // 1/sqrt(32)

    int i = half ? mid : beg;
    const int i1 = half ? end : mid;

    for (; i + 1 < i1; i += 2) {
        int s0 = __builtin_nontemporal_load(ssorted + i);
        int s1 = __builtin_nontemporal_load(ssorted + i + 1);
        const unsigned short* p0 = KV + (size_t)s0 * 512 + hl * 8;
        const unsigned short* p1 = KV + (size_t)s1 * 512 + hl * 8;
        ushortx8 k0 = *(const ushortx8*)p0;        ushortx8 v0 = *(const ushortx8*)(p0 + 256);
        ushortx8 k1 = *(const ushortx8*)p1;        ushortx8 v1 = *(const ushortx8*)(p1 + 256);

        float d0 = 0.f, d1 = 0.f;
#pragma unroll
        for (int j = 0; j < 8; j++) {
            d0 = fmaf(bf2f(k0[j]), q[j], d0);
            d1 = fmaf(bf2f(k1[j]), q[j], d1);
        }
        d0 += __shfl_xor(d0, 1); d0 += __shfl_xor(d0, 2);
        d1 += __shfl_xor(d1, 1); d1 += __shfl_xor(d1, 2);
        float e0 = __expf(fminf(5.f, fmaxf(-5.f, d0 * scale)));
        float e1 = __expf(fminf(5.f, fmaxf(-5.f, d1 * scale)));
        z += e0 + e1;
#pragma unroll
        for (int j = 0; j < 8; j++) {
            acc[j] = fmaf(e0, bf2f(v0[j]), acc[j]);
            acc[j] = fmaf(e1, bf2f(v1[j]), acc[j]);
        }
    }
    for (; i < i1; i++) {
        int s = __builtin_nontemporal_load(ssorted + i);
        const unsigned short* p = KV + (size_t)s * 512 + hl * 8;
        ushortx8 k8 = *(const ushortx8*)p;
        ushortx8 v8 = *(const ushortx8*)(p + 256);
        float d = 0.f;
#pragma unroll
        for (int j = 0; j < 8; j++) d = fmaf(bf2f(k8[j]), q[j], d);
        d += __shfl_xor(d, 1); d += __shfl_xor(d, 2);
        float sc = __expf(fminf(5.f, fmaxf(-5.f, d * scale)));
        z += sc;
#pragma unroll
        for (int j = 0; j < 8; j++) acc[j] = fmaf(sc, bf2f(v8[j]), acc[j]);
    }

    z += __shfl_xor(z, 32);
#pragma unroll
    for (int j = 0; j < 8; j++) acc[j] += __shfl_xor(acc[j], 32);

    if (half == 0) {
        float inv = (z > 0.f) ? 1.f / z : 0.f;
        floatx4 o0, o1;
        o0[0] = acc[0] * inv; o0[1] = acc[1] * inv; o0[2] = acc[2] * inv; o0[3] = acc[3] * inv;
        o1[0] = acc[4] * inv; o1[1] = acc[5] * inv; o1[2] = acc[6] * inv; o1[3] = acc[7] * inv;
        floatx4* op = (floatx4*)(out + (size_t)n * 256 + hl * 8);
        __builtin_nontemporal_store(o0, op);
        __builtin_nontemporal_store(o1, op + 1);
    }
}

extern "C" void kernel_launch(void* const* d_in, const int* in_sizes, int n_in,
                              void* d_out, int out_size, void* d_ws, size_t ws_size,
                              hipStream_t stream) {
    const float* h  = (const float*)d_in[0];
    const float* Wq = (const float*)d_in[1];
    const float* bq = (const float*)d_in[2];
    const float* Wk = (const float*)d_in[3];
    const float* bk = (const float*)d_in[4];
    const float* Wv = (const float*)d_in[5];
    const float* bv = (const float*)d_in[6];
    const int*   src = (const int*)d_in[7];
    const int*   dst = (const int*)d_in[8];
    float* out = (float*)d_out;

    const int N = in_sizes[0] / 256;
    const int E = in_sizes[7];

    size_t off = 0;
    auto alloc = [&](size_t bytes) {
        void* p = (char*)d_ws + off;
        off += (bytes + 255) & ~(size_t)255;
        return p;
    };
    unsigned short* Qb = (unsigned short*)alloc((size_t)N * 256 * 2);
    unsigned short* KV = (unsigned short*)alloc((size_t)N * 512 * 2);
    unsigned short* hb = (unsigned short*)alloc((size_t)N * 256 * 2);
    unsigned short* Wb = (unsigned short*)alloc((size_t)768 * 256 * 2);
    int* deg      = (int*)alloc((size_t)N * 4);
    int* offsets  = (int*)alloc((size_t)(N + 1) * 4);
    int* cursor   = (int*)alloc((size_t)N * 4);
    unsigned short* ssorted = (unsigned short*)alloc((size_t)E * 2);

    // 0) bf16 conversions
    int n4h = (N * 256) / 4;
    cvt_bf16<<<(n4h + 255) / 256, 256, 0, stream>>>(h, hb, n4h);
    int n4w = (256 * 256) / 4;
    dim3 wgrid((n4w + 255) / 256, 3);
    cvt_w3<<<wgrid, 256, 0, stream>>>(Wq, Wk, Wv, Wb, n4w);

    // 1) QKV projections (bf16 MFMA, BK=64)
    dim3 ggrid((N + 127) / 128, 6);
    qkv_gemm_mfma<<<ggrid, 256, 0, stream>>>(hb, Wb, bq, bk, bv, Qb, KV, N);

    // 2) CSR build
    hipMemsetAsync(deg, 0, (size_t)N * 4, stream);
    int eblocks4 = (E + 1023) / 1024;
    count_deg<<<eblocks4, 256, 0, stream>>>(dst, deg, E);
    scan_fused<<<1, 1024, 0, stream>>>(deg, offsets, cursor, N, E);
    scatter_edges<<<eblocks4, 256, 0, stream>>>(dst, src, cursor, ssorted, E);

    // 3) fused score/softmax/aggregate
    int ablocks = (N + 3) / 4;
    edge_agg<<<ablocks, 256, 0, stream>>>(Qb, KV, offsets, ssorted, out, N);
}

// Round 8
// 362.689 us; speedup vs baseline: 1.3007x; 1.3007x over previous
//
#include <hip/hip_runtime.h>
#include <hip/hip_bf16.h>

// N=50000 nodes, IN=256, H=8 heads, D=32, HD=256, E=800000 edges (from in_sizes).

typedef __attribute__((ext_vector_type(8))) short short8;
typedef __attribute__((ext_vector_type(8))) unsigned short ushortx8;
typedef __attribute__((ext_vector_type(4))) unsigned short ushortx4;
typedef __attribute__((ext_vector_type(4))) float floatx4;
typedef __attribute__((ext_vector_type(4))) int intx4;

__device__ __forceinline__ void g2l16(const void* g, void* l) {
    __builtin_amdgcn_global_load_lds(
        (const __attribute__((address_space(1))) unsigned int*)g,
        (__attribute__((address_space(3))) unsigned int*)l, 16, 0, 0);
}

__device__ __forceinline__ float bf2f(unsigned short u) {
    union { unsigned int i; float f; } c; c.i = ((unsigned int)u) << 16; return c.f;
}
__device__ __forceinline__ unsigned short f2bf(float f) {
    __hip_bfloat16 b = __float2bfloat16(f);
    return *reinterpret_cast<unsigned short*>(&b);
}

// ---- fp32 -> bf16 conversions ----
__global__ __launch_bounds__(256) void cvt_bf16(const float* __restrict__ src,
                                                unsigned short* __restrict__ dst, int n4) {
    int i = blockIdx.x * 256 + threadIdx.x;
    if (i >= n4) return;
    floatx4 f = __builtin_nontemporal_load((const floatx4*)src + i);
    ushortx4 u;
    u.x = f2bf(f.x); u.y = f2bf(f.y); u.z = f2bf(f.z); u.w = f2bf(f.w);
    ((ushortx4*)dst)[i] = u;
}

__global__ __launch_bounds__(256) void cvt_w3(const float* __restrict__ Wq,
                                              const float* __restrict__ Wk,
                                              const float* __restrict__ Wv,
                                              unsigned short* __restrict__ Wb, int n4) {
    int mat = blockIdx.y;
    const float* src = (mat == 0) ? Wq : (mat == 1) ? Wk : Wv;
    int i = blockIdx.x * 256 + threadIdx.x;
    if (i >= n4) return;
    floatx4 f = __builtin_nontemporal_load((const floatx4*)src + i);
    ushortx4 u;
    u.x = f2bf(f.x); u.y = f2bf(f.y); u.z = f2bf(f.z); u.w = f2bf(f.w);
    ((ushortx4*)(Wb + (size_t)mat * 65536))[i] = u;
}

// ---- bf16 MFMA QKV projection, BK=64 (r7-keeper) ----
// grid: (ceil(N/128), 6). Block 256 = 4 waves; each wave 64x64 (4x4 MFMA 16x16x32).
// 32 MFMA per barrier pair. Q written bf16 NT; K,V bf16 interleaved KV[N][512].
__global__ __launch_bounds__(256) void qkv_gemm_mfma(
    const unsigned short* __restrict__ hb, const unsigned short* __restrict__ Wb,
    const float* __restrict__ bq, const float* __restrict__ bk, const float* __restrict__ bv,
    unsigned short* __restrict__ Qb, unsigned short* __restrict__ KV, int N)
{
    __shared__ unsigned short Ast[2][128 * 32];
    __shared__ unsigned short Bst[2][128 * 32];

    const int tid = threadIdx.x;
    const int wave = tid >> 6;
    const int lane = tid & 63;
    const int m = lane & 15;
    const int q = lane >> 4;
    const int wr = wave >> 1, wc = wave & 1;

    const int mbase = blockIdx.x * 128;
    const int mat = blockIdx.y >> 1;                 // 0:Q 1:K 2:V
    const int colbase = (blockIdx.y & 1) * 128;
    const int wrow0 = blockIdx.y * 128;

    const float* bias = (mat == 0) ? bq : (mat == 1) ? bk : bv;

    floatx4 acc[4][4] = {};

    for (int kk = 0; kk < 256; kk += 64) {
#pragma unroll
        for (int c = 0; c < 2; c++) {
#pragma unroll
            for (int t = 0; t < 2; t++) {
                int f = t * 256 + tid;
                int row = f >> 2, kc = f & 3;
                int grow = mbase + row; if (grow > N - 1) grow = N - 1;
                g2l16(hb + (size_t)grow * 256 + kk + c * 32 + kc * 8,
                      Ast[c] + (size_t)(t * 256 + wave * 64) * 8);
            }
#pragma unroll
            for (int t = 0; t < 2; t++) {
                int f = t * 256 + tid;
                int row = f >> 2, kc = f & 3;
                g2l16(Wb + (size_t)(wrow0 + row) * 256 + kk + c * 32 + kc * 8,
                      Bst[c] + (size_t)(t * 256 + wave * 64) * 8);
            }
        }
        __syncthreads();

#pragma unroll
        for (int c = 0; c < 2; c++) {
            short8 a[4], b[4];
#pragma unroll
            for (int i = 0; i < 4; i++) {
                int r = wr * 64 + i * 16 + m;
                a[i] = *(const short8*)&Ast[c][r * 32 + q * 8];
            }
#pragma unroll
            for (int j = 0; j < 4; j++) {
                int cc = wc * 64 + j * 16 + m;
                b[j] = *(const short8*)&Bst[c][cc * 32 + q * 8];
            }
#pragma unroll
            for (int i = 0; i < 4; i++)
#pragma unroll
                for (int j = 0; j < 4; j++)
                    acc[i][j] = __builtin_amdgcn_mfma_f32_16x16x32_bf16(a[i], b[j], acc[i][j], 0, 0, 0);
        }
        __syncthreads();
    }

    float bvj[4];
#pragma unroll
    for (int j = 0; j < 4; j++) bvj[j] = bias[colbase + wc * 64 + j * 16 + m];

    const int col0 = colbase + wc * 64 + m;
    // C/D layout: col = lane&15, row = (lane>>4)*4 + reg
#pragma unroll
    for (int i = 0; i < 4; i++) {
#pragma unroll
        for (int r = 0; r < 4; r++) {
            int grow = mbase + wr * 64 + i * 16 + q * 4 + r;
            if (grow < N) {
                if (mat == 0) {
                    unsigned short* op = Qb + (size_t)grow * 256 + col0;
#pragma unroll
                    for (int j = 0; j < 4; j++)
                        __builtin_nontemporal_store(f2bf(acc[i][j][r] + bvj[j]), op + j * 16);
                } else {
                    unsigned short* op = KV + (size_t)grow * 512 + ((mat == 2) ? 256 : 0) + col0;
#pragma unroll
                    for (int j = 0; j < 4; j++)
                        op[j * 16] = f2bf(acc[i][j][r] + bvj[j]);
                }
            }
        }
    }
}

// ---- CSR build ----
__global__ void count_deg(const int* __restrict__ dst, int* __restrict__ deg, int E) {
    int e4 = (blockIdx.x * 256 + threadIdx.x) * 4;
    if (e4 + 3 < E) {
        intx4 d = __builtin_nontemporal_load((const intx4*)(dst + e4));
        atomicAdd(&deg[d.x], 1); atomicAdd(&deg[d.y], 1);
        atomicAdd(&deg[d.z], 1); atomicAdd(&deg[d.w], 1);
    } else {
        for (int e = e4; e < E; e++) atomicAdd(&deg[dst[e]], 1);
    }
}

#define SCAN_CHUNK 2048  // 256 threads x 8

__global__ void scan_phase1(const int* __restrict__ deg, int* __restrict__ partials, int N) {
    __shared__ int sdata[256];
    int base = blockIdx.x * SCAN_CHUNK;
    int sum = 0;
#pragma unroll
    for (int i = 0; i < 8; i++) {
        int idx = base + threadIdx.x + i * 256;
        if (idx < N) sum += deg[idx];
    }
    sdata[threadIdx.x] = sum;
    __syncthreads();
    for (int s = 128; s > 0; s >>= 1) {
        if (threadIdx.x < (unsigned)s) sdata[threadIdx.x] += sdata[threadIdx.x + s];
        __syncthreads();
    }
    if (threadIdx.x == 0) partials[blockIdx.x] = sdata[0];
}

__global__ void scan_phase2(int* __restrict__ partials, int nb) {
    if (threadIdx.x == 0 && blockIdx.x == 0) {
        int run = 0;
        for (int i = 0; i < nb; i++) { int v = partials[i]; partials[i] = run; run += v; }
    }
}

__global__ void scan_phase3(const int* __restrict__ deg, const int* __restrict__ partials,
                            int* __restrict__ offsets, int* __restrict__ cursor, int N, int E) {
    __shared__ int sdata[256];
    int base = blockIdx.x * SCAN_CHUNK;
    int vals[8];
    int sum = 0;
#pragma unroll
    for (int i = 0; i < 8; i++) {
        int idx = base + threadIdx.x * 8 + i;
        vals[i] = (idx < N) ? deg[idx] : 0;
        sum += vals[i];
    }
    sdata[threadIdx.x] = sum;
    __syncthreads();
    for (int s = 1; s < 256; s <<= 1) {
        int v = sdata[threadIdx.x];
        int add = (threadIdx.x >= (unsigned)s) ? sdata[threadIdx.x - s] : 0;
        __syncthreads();
        sdata[threadIdx.x] = v + add;
        __syncthreads();
    }
    int excl = (threadIdx.x == 0) ? 0 : sdata[threadIdx.x - 1];
    int run = partials[blockIdx.x] + excl;
#pragma unroll
    for (int i = 0; i < 8; i++) {
        int idx = base + threadIdx.x * 8 + i;
        if (idx < N) { offsets[idx] = run; cursor[idx] = run; }
        run += vals[i];
    }
    if (blockIdx.x == 0 && threadIdx.x == 0) offsets[N] = E;
}

// src node ids fit in uint16 (N < 65536)
__global__ void scatter_edges(const int* __restrict__ dst, const int* __restrict__ src,
                              int* __restrict__ cursor, unsigned short* __restrict__ ssorted,
                              int E) {
    int e4 = (blockIdx.x * 256 + threadIdx.x) * 4;
    if (e4 + 3 < E) {
        intx4 d = __builtin_nontemporal_load((const intx4*)(dst + e4));
        intx4 s = __builtin_nontemporal_load((const intx4*)(src + e4));
        ssorted[atomicAdd(&cursor[d.x], 1)] = (unsigned short)s.x;
        ssorted[atomicAdd(&cursor[d.y], 1)] = (unsigned short)s.y;
        ssorted[atomicAdd(&cursor[d.z], 1)] = (unsigned short)s.z;
        ssorted[atomicAdd(&cursor[d.w], 1)] = (unsigned short)s.w;
    } else {
        for (int e = e4; e < E; e++)
            ssorted[atomicAdd(&cursor[dst[e]], 1)] = (unsigned short)src[e];
    }
}

// ---- fused score + segment-softmax + aggregation (r6-proven structure) ----
__global__ __launch_bounds__(256) void edge_agg(
    const unsigned short* __restrict__ Qb, const unsigned short* __restrict__ KV,
    const int* __restrict__ offsets, const unsigned short* __restrict__ ssorted,
    float* __restrict__ out, int N)
{
    const int wave = threadIdx.x >> 6;
    const int lane = threadIdx.x & 63;
    const int half = lane >> 5;
    const int hl = lane & 31;
    const int n = blockIdx.x * 4 + wave;
    if (n >= N) return;

    float q[8];
    {
        ushortx8 qu = __builtin_nontemporal_load((const ushortx8*)(Qb + (size_t)n * 256 + hl * 8));
#pragma unroll
        for (int j = 0; j < 8; j++) q[j] = bf2f(qu[j]);
    }

    float acc[8] = {};
    float z = 0.f;
    const int beg = offsets[n], end = offsets[n + 1];
    const int len = end - beg;
    const int mid = beg + ((len + 1) >> 1);
    const float scale = 0.17677669529663687f;  // 1/sqrt(32)

    int i = half ? mid : beg;
    const int i1 = half ? end : mid;

    for (; i + 1 < i1; i += 2) {
        int s0 = __builtin_nontemporal_load(ssorted + i);
        int s1 = __builtin_nontemporal_load(ssorted + i + 1);
        const unsigned short* p0 = KV + (size_t)s0 * 512 + hl * 8;
        const unsigned short* p1 = KV + (size_t)s1 * 512 + hl * 8;
        ushortx8 k0 = *(const ushortx8*)p0;        ushortx8 v0 = *(const ushortx8*)(p0 + 256);
        ushortx8 k1 = *(const ushortx8*)p1;        ushortx8 v1 = *(const ushortx8*)(p1 + 256);

        float d0 = 0.f, d1 = 0.f;
#pragma unroll
        for (int j = 0; j < 8; j++) {
            d0 = fmaf(bf2f(k0[j]), q[j], d0);
            d1 = fmaf(bf2f(k1[j]), q[j], d1);
        }
        d0 += __shfl_xor(d0, 1); d0 += __shfl_xor(d0, 2);
        d1 += __shfl_xor(d1, 1); d1 += __shfl_xor(d1, 2);
        float e0 = __expf(fminf(5.f, fmaxf(-5.f, d0 * scale)));
        float e1 = __expf(fminf(5.f, fmaxf(-5.f, d1 * scale)));
        z += e0 + e1;
#pragma unroll
        for (int j = 0; j < 8; j++) {
            acc[j] = fmaf(e0, bf2f(v0[j]), acc[j]);
            acc[j] = fmaf(e1, bf2f(v1[j]), acc[j]);
        }
    }
    for (; i < i1; i++) {
        int s = __builtin_nontemporal_load(ssorted + i);
        const unsigned short* p = KV + (size_t)s * 512 + hl * 8;
        ushortx8 k8 = *(const ushortx8*)p;
        ushortx8 v8 = *(const ushortx8*)(p + 256);
        float d = 0.f;
#pragma unroll
        for (int j = 0; j < 8; j++) d = fmaf(bf2f(k8[j]), q[j], d);
        d += __shfl_xor(d, 1); d += __shfl_xor(d, 2);
        float sc = __expf(fminf(5.f, fmaxf(-5.f, d * scale)));
        z += sc;
#pragma unroll
        for (int j = 0; j < 8; j++) acc[j] = fmaf(sc, bf2f(v8[j]), acc[j]);
    }

    z += __shfl_xor(z, 32);
#pragma unroll
    for (int j = 0; j < 8; j++) acc[j] += __shfl_xor(acc[j], 32);

    if (half == 0) {
        float inv = (z > 0.f) ? 1.f / z : 0.f;
        floatx4 o0, o1;
        o0[0] = acc[0] * inv; o0[1] = acc[1] * inv; o0[2] = acc[2] * inv; o0[3] = acc[3] * inv;
        o1[0] = acc[4] * inv; o1[1] = acc[5] * inv; o1[2] = acc[6] * inv; o1[3] = acc[7] * inv;
        floatx4* op = (floatx4*)(out + (size_t)n * 256 + hl * 8);
        __builtin_nontemporal_store(o0, op);
        __builtin_nontemporal_store(o1, op + 1);
    }
}

extern "C" void kernel_launch(void* const* d_in, const int* in_sizes, int n_in,
                              void* d_out, int out_size, void* d_ws, size_t ws_size,
                              hipStream_t stream) {
    const float* h  = (const float*)d_in[0];
    const float* Wq = (const float*)d_in[1];
    const float* bq = (const float*)d_in[2];
    const float* Wk = (const float*)d_in[3];
    const float* bk = (const float*)d_in[4];
    const float* Wv = (const float*)d_in[5];
    const float* bv = (const float*)d_in[6];
    const int*   src = (const int*)d_in[7];
    const int*   dst = (const int*)d_in[8];
    float* out = (float*)d_out;

    const int N = in_sizes[0] / 256;
    const int E = in_sizes[7];

    size_t off = 0;
    auto alloc = [&](size_t bytes) {
        void* p = (char*)d_ws + off;
        off += (bytes + 255) & ~(size_t)255;
        return p;
    };
    unsigned short* Qb = (unsigned short*)alloc((size_t)N * 256 * 2);
    unsigned short* KV = (unsigned short*)alloc((size_t)N * 512 * 2);
    unsigned short* hb = (unsigned short*)alloc((size_t)N * 256 * 2);
    unsigned short* Wb = (unsigned short*)alloc((size_t)768 * 256 * 2);
    int* deg      = (int*)alloc((size_t)N * 4);
    int* offsets  = (int*)alloc((size_t)(N + 1) * 4);
    int* cursor   = (int*)alloc((size_t)N * 4);
    int* partials = (int*)alloc(1024 * 4);
    unsigned short* ssorted = (unsigned short*)alloc((size_t)E * 2);

    // 0) bf16 conversions
    int n4h = (N * 256) / 4;
    cvt_bf16<<<(n4h + 255) / 256, 256, 0, stream>>>(h, hb, n4h);
    int n4w = (256 * 256) / 4;
    dim3 wgrid((n4w + 255) / 256, 3);
    cvt_w3<<<wgrid, 256, 0, stream>>>(Wq, Wk, Wv, Wb, n4w);

    // 1) QKV projections (bf16 MFMA, BK=64)
    dim3 ggrid((N + 127) / 128, 6);
    qkv_gemm_mfma<<<ggrid, 256, 0, stream>>>(hb, Wb, bq, bk, bv, Qb, KV, N);

    // 2) CSR build (3-phase multi-block scan — r6-proven)
    hipMemsetAsync(deg, 0, (size_t)N * 4, stream);
    int eblocks4 = (E + 1023) / 1024;
    count_deg<<<eblocks4, 256, 0, stream>>>(dst, deg, E);

    int nscan = (N + SCAN_CHUNK - 1) / SCAN_CHUNK;
    scan_phase1<<<nscan, 256, 0, stream>>>(deg, partials, N);
    scan_phase2<<<1, 64, 0, stream>>>(partials, nscan);
    scan_phase3<<<nscan, 256, 0, stream>>>(deg, partials, offsets, cursor, N, E);

    scatter_edges<<<eblocks4, 256, 0, stream>>>(dst, src, cursor, ssorted, E);

    // 3) fused score/softmax/aggregate
    int ablocks = (N + 3) / 4;
    edge_agg<<<ablocks, 256, 0, stream>>>(Qb, KV, offsets, ssorted, out, N);
}